// Round 4
// baseline (1153.540 us; speedup 1.0000x reference)
//
#include <hip/hip_runtime.h>
#include <hip/hip_bf16.h>
#include <math.h>

#define NEG 0.01f

typedef __attribute__((ext_vector_type(8))) short short8;
typedef __attribute__((ext_vector_type(4))) float f32x4;
typedef unsigned short ushort;

#define MFMA(a,b,c) __builtin_amdgcn_mfma_f32_16x16x32_bf16(a,b,c,0,0,0)

__device__ __forceinline__ float leaky(float x){ return x >= 0.f ? x : NEG*x; }
__device__ __forceinline__ ushort b16(float f){
  unsigned int u = __float_as_uint(f);
  unsigned int r = (u + 0x7FFF + ((u >> 16) & 1)) >> 16;
  return (ushort)r;
}
// manual RNE pack (verified in rounds 1-2); cvt_pk asm was the prime suspect for r3 failure
__device__ __forceinline__ short8 pack8(const float* f){
  union { ushort s[8]; short8 v; } t;
  #pragma unroll
  for (int j = 0; j < 8; j++) t.s[j] = b16(f[j]);
  return t.v;
}

// ---------------- CSR build ----------------
__global__ void k_deg(const int* __restrict__ dst, int* __restrict__ deg, int E){
  int e = blockIdx.x*256 + threadIdx.x;
  if (e < E) atomicAdd(&deg[dst[e]], 1);
}

// chunk-serial scan: 1 block
__global__ __launch_bounds__(1024) void k_scan(const int* __restrict__ deg, int* __restrict__ off, int N){
  __shared__ int sums[1024];
  int tid = threadIdx.x;
  int per = (N + 1023) / 1024;
  int s0 = tid * per;
  int local = 0;
  for (int i = 0; i < per; i++){
    int idx = s0 + i;
    if (idx < N) local += deg[idx];
  }
  sums[tid] = local;
  __syncthreads();
  for (int s = 1; s < 1024; s <<= 1){
    int t = (tid >= s) ? sums[tid - s] : 0;
    __syncthreads();
    sums[tid] += t;
    __syncthreads();
  }
  int run = sums[tid] - local;   // exclusive base
  for (int i = 0; i < per; i++){
    int idx = s0 + i;
    if (idx < N){ off[idx] = run; run += deg[idx]; }
  }
  if (tid == 1023) off[N] = run;
}

__global__ void k_fill(const int* __restrict__ dst, const int* __restrict__ off,
                       int* __restrict__ cursor, int* __restrict__ eids, int E){
  int e = blockIdx.x*256 + threadIdx.x;
  if (e < E){
    int d = dst[e];
    int p = atomicAdd(&cursor[d], 1);
    eids[off[d] + p] = e;
  }
}

// ---------------- weight prep: transpose + bf16, layouts [O][K] k-contiguous ----------------
__global__ void k_prep2(const float* __restrict__ W_ni, const float* __restrict__ W_nj,
                        const float* __restrict__ W_fij, const float* __restrict__ W_node,
                        const float* __restrict__ ek_c, const float* __restrict__ nk_c,
                        const float* __restrict__ on_c, const float* __restrict__ oe_c,
                        ushort* __restrict__ Bni, ushort* __restrict__ Bnj,
                        ushort* __restrict__ Bfij, ushort* __restrict__ BE,
                        ushort* __restrict__ BN_, ushort* __restrict__ BW,
                        ushort* __restrict__ BO, ushort* __restrict__ BOE){
  int t = blockIdx.x*256 + threadIdx.x;
  if (t < 16384){ int o = t >> 7, i = t & 127; Bni[t] = b16(W_ni[i*128 + o]); return; }
  t -= 16384;
  if (t < 16384){ int o = t >> 7, i = t & 127; Bnj[t] = b16(W_nj[i*128 + o]); return; }
  t -= 16384;
  if (t < 8192){ int o = t >> 6, i = t & 63; Bfij[t] = b16(W_fij[i*128 + o]); return; }
  t -= 8192;
  if (t < 32768){ int o = t >> 8, k = t & 255; int tt = k >> 7, i = k & 127;
    BE[t] = b16(ek_c[((tt*128 + o) << 7) + i]); return; }
  t -= 32768;
  if (t < 73728){ int o = t / 384, k = t % 384; int tt = (k >= 192), i = k - tt*192;
    BN_[t] = b16(nk_c[(tt*192 + o)*192 + i]); return; }
  t -= 73728;
  if (t < 98304){ int o = t / 192, i = t % 192; BW[t] = b16(W_node[i*512 + o]); return; }
  t -= 98304;
  if (t < 131072){ int o = t >> 10, k = t & 1023; int tt = k >> 9, q = k & 511, i = q >> 2, g = q & 3;
    BO[t] = b16(on_c[(((tt*128 + o) << 7) + i)*4 + g]); return; }
  t -= 131072;
  if (t < 8192){ int o = t >> 8, k = t & 255; int tt = k >> 7, q = k & 127, i = q >> 2, g = q & 3;
    BOE[t] = b16(oe_c[((tt*32 + o)*32 + i)*4 + g]); return; }
}

// ---------------- dense bf16-MFMA GEMM: 64x64 tile, BK=32, 4 waves ----------------
template<int MODE>
__global__ __launch_bounds__(256) void k_mm(
    const float* __restrict__ A, int lda, const float* __restrict__ A2,
    const ushort* __restrict__ B,            // [Ncols][K] bf16 k-contiguous
    float* __restrict__ C, int ldc, const float* __restrict__ bias,
    int M, int K)
{
  __shared__ __align__(16) ushort As[64*40];
  const int tid = threadIdx.x;
  const int lane = tid & 63, w = tid >> 6;
  const int l15 = lane & 15, kg = lane >> 4;
  const int r0 = blockIdx.x * 64;
  const int c0 = blockIdx.y * 64;
  const int rg = (w & 1) * 2;
  const int cgb = (w >> 1) * 2;
  f32x4 acc[2][2] = {};
  const int srow = tid >> 2;
  const int kk = (tid & 3) * 8;

  for (int k0 = 0; k0 < K; k0 += 32){
    { // stage A tile (featurized)
      int row = r0 + srow;
      float v[8];
      if (MODE == 0){
        if (row < M){
          const float* p = A + (size_t)row*lda + k0 + kk;
          float4 a = *(const float4*)p, b = *(const float4*)(p+4);
          v[0]=a.x; v[1]=a.y; v[2]=a.z; v[3]=a.w;
          v[4]=b.x; v[5]=b.y; v[6]=b.z; v[7]=b.w;
        } else { for (int j=0;j<8;j++) v[j]=0.f; }
      } else if (MODE == 1){
        int k = k0 + kk;
        int tt = k >> 9, i = (k & 511) >> 2;
        float x0 = 0.f, x1 = 0.f;
        if (row < M){ x0 = A[(size_t)row*128 + i]; x1 = A[(size_t)row*128 + i + 1]; }
        #pragma unroll
        for (int g = 1; g <= 4; g++){
          v[g-1] = tt ? __sinf(x0*(float)g) : __cosf(x0*(float)g);
          v[3+g] = tt ? __sinf(x1*(float)g) : __cosf(x1*(float)g);
        }
      } else {
        int k = k0 + kk;
        int tt = (k >= 192), i = k - tt*192;
        float xv8[8] = {0,0,0,0,0,0,0,0};
        if (row < M){
          const float* sp = (i < 128) ? (A + (size_t)row*128 + i) : (A2 + (size_t)row*64 + (i - 128));
          float4 a = *(const float4*)sp, b = *(const float4*)(sp+4);
          xv8[0]=a.x; xv8[1]=a.y; xv8[2]=a.z; xv8[3]=a.w;
          xv8[4]=b.x; xv8[5]=b.y; xv8[6]=b.z; xv8[7]=b.w;
        }
        #pragma unroll
        for (int j = 0; j < 8; j++)
          xv8[j] = tt ? __sinf(xv8[j]) : __cosf(xv8[j]);
        #pragma unroll
        for (int j = 0; j < 8; j++) v[j] = xv8[j];
      }
      *(short8*)&As[srow*40 + kk] = pack8(v);
    }
    __syncthreads();
    short8 afr[2], bfr[2];
    #pragma unroll
    for (int q = 0; q < 2; q++)
      afr[q] = *(const short8*)&As[((rg+q)*16 + l15)*40 + kg*8];
    #pragma unroll
    for (int q = 0; q < 2; q++)
      bfr[q] = *(const short8*)(B + (size_t)(c0 + (cgb+q)*16 + l15)*K + k0 + kg*8);
    #pragma unroll
    for (int i = 0; i < 2; i++)
      #pragma unroll
      for (int j = 0; j < 2; j++)
        acc[i][j] = MFMA(afr[i], bfr[j], acc[i][j]);
    __syncthreads();
  }
  #pragma unroll
  for (int i = 0; i < 2; i++){
    #pragma unroll
    for (int j = 0; j < 2; j++){
      int col = c0 + (cgb+j)*16 + l15;
      float bv = bias ? bias[col] : 0.f;
      #pragma unroll
      for (int r = 0; r < 4; r++){
        int row = r0 + (rg+i)*16 + kg*4 + r;
        if (row < M) C[(size_t)row*ldc + col] = acc[i][j][r] + bv;
      }
    }
  }
}

// ---------------- fused edge kernel: wave-independent, 16 edges/wave, 0 barriers ----------------
__global__ __launch_bounds__(256) void k_edge(
    const float* __restrict__ P,          // [N][256] = [P_ni | P_nj]
    const float* __restrict__ ef,         // [E][64]
    const int* __restrict__ src, const int* __restrict__ dst,
    const ushort* __restrict__ Bfij,      // [128][64]
    const ushort* __restrict__ BE,        // [128][256]
    const ushort* __restrict__ BOE,      // [32][256]
    const float* __restrict__ ek_b, const float* __restrict__ bias_edge,
    const float* __restrict__ attn, const float* __restrict__ oe_b,
    float* __restrict__ scores,           // [E][4]
    float* __restrict__ out_edge,         // [E][32]
    int E)
{
  __shared__ __align__(16) float shmem[4*2112];   // per-wave 16x132 f32 (x), overlaid 16x36 (fsum)
  const int tid = threadIdx.x;
  const int lane = tid & 63, w = tid >> 6;
  const int l15 = lane & 15, kg = lane >> 4;
  const int e0 = (blockIdx.x*4 + w) * 16;
  if (e0 >= E) return;
  float* xw  = shmem + w*2112;   // stride 132
  float* fsw = xw;               // stride 36 (overlay, used after x consumed)

  // per-lane small tables (L2-hot broadcasts)
  int sr[4], dr[4];
  #pragma unroll
  for (int r = 0; r < 4; r++){ sr[r] = src[e0 + kg*4 + r]; dr[r] = dst[e0 + kg*4 + r]; }
  float attnv[8], ekbv[8];
  #pragma unroll
  for (int cg = 0; cg < 8; cg++){
    int col = cg*16 + l15;
    attnv[cg] = attn[col];
    ekbv[cg]  = ek_b[col] + bias_edge[col];
  }
  float oebv[2] = { oe_b[l15], oe_b[16 + l15] };

  // ---- phase 1: acc = P_ni[src] + P_nj[dst]; MFMA += ef @ Bfij
  f32x4 acc[8];
  #pragma unroll
  for (int cg = 0; cg < 8; cg++){
    int col = cg*16 + l15;
    #pragma unroll
    for (int r = 0; r < 4; r++)
      acc[cg][r] = P[(size_t)sr[r]*256 + col] + P[(size_t)dr[r]*256 + 128 + col];
  }
  short8 afe[2];
  #pragma unroll
  for (int ks = 0; ks < 2; ks++){
    const float* p = ef + (size_t)(e0 + l15)*64 + ks*32 + kg*8;
    float4 u0 = *(const float4*)p, u1 = *(const float4*)(p+4);
    float tv[8] = {u0.x,u0.y,u0.z,u0.w,u1.x,u1.y,u1.z,u1.w};
    afe[ks] = pack8(tv);
  }
  __builtin_amdgcn_s_setprio(1);
  #pragma unroll
  for (int cg = 0; cg < 8; cg++){
    #pragma unroll
    for (int ks = 0; ks < 2; ks++){
      short8 bf = *(const short8*)(Bfij + (size_t)(cg*16 + l15)*64 + ks*32 + kg*8);
      acc[cg] = MFMA(afe[ks], bf, acc[cg]);
    }
  }
  __builtin_amdgcn_s_setprio(0);
  // write x to LDS (transpose for phase 3)
  #pragma unroll
  for (int cg = 0; cg < 8; cg++)
    #pragma unroll
    for (int r = 0; r < 4; r++)
      xw[(kg*4 + r)*132 + cg*16 + l15] = acc[cg][r];
  __builtin_amdgcn_sched_barrier(0);   // pin LDS writes before cross-lane reads (DS FIFO orders in HW)

  // ---- phase 3 A-frags: read own row (e = l15), trig, pack
  float xv[4][8];
  #pragma unroll
  for (int s = 0; s < 4; s++){
    float4 q0 = *(const float4*)&xw[l15*132 + s*32 + kg*8];
    float4 q1 = *(const float4*)&xw[l15*132 + s*32 + kg*8 + 4];
    xv[s][0]=q0.x; xv[s][1]=q0.y; xv[s][2]=q0.z; xv[s][3]=q0.w;
    xv[s][4]=q1.x; xv[s][5]=q1.y; xv[s][6]=q1.z; xv[s][7]=q1.w;
  }
  short8 afr[8];
  #pragma unroll
  for (int s = 0; s < 4; s++){
    float tc[8], ts[8];
    #pragma unroll
    for (int j = 0; j < 8; j++){ tc[j] = __cosf(xv[s][j]); ts[j] = __sinf(xv[s][j]); }
    afr[s]     = pack8(tc);
    afr[s + 4] = pack8(ts);
  }
  // ---- phase 3 MFMA: f = feats @ BE + ekb
  f32x4 facc[8];
  __builtin_amdgcn_s_setprio(1);
  #pragma unroll
  for (int cg = 0; cg < 8; cg++){
    f32x4 a = { ekbv[cg], ekbv[cg], ekbv[cg], ekbv[cg] };
    #pragma unroll
    for (int ks = 0; ks < 8; ks++){
      short8 bf = *(const short8*)(BE + (size_t)(cg*16 + l15)*256 + ks*32 + kg*8);
      a = MFMA(afr[ks], bf, a);
    }
    facc[cg] = a;
  }
  __builtin_amdgcn_s_setprio(0);
  float fv[8][4];
  #pragma unroll
  for (int cg = 0; cg < 8; cg++)
    #pragma unroll
    for (int r = 0; r < 4; r++)
      fv[cg][r] = leaky(facc[cg][r]);

  // ---- scores: butterfly reduce within each kg group (16 lanes)
  float p[4][4] = {};
  #pragma unroll
  for (int cg = 0; cg < 8; cg++){
    int hh = cg >> 1;
    #pragma unroll
    for (int r = 0; r < 4; r++) p[hh][r] += fv[cg][r] * attnv[cg];
  }
  #pragma unroll
  for (int m = 1; m <= 8; m <<= 1)
    #pragma unroll
    for (int hh = 0; hh < 4; hh++)
      #pragma unroll
      for (int r = 0; r < 4; r++)
        p[hh][r] += __shfl_xor(p[hh][r], m, 64);
  {
    float outv = 0.f;
    #pragma unroll
    for (int hh = 0; hh < 4; hh++)
      #pragma unroll
      for (int rr = 0; rr < 4; rr++)
        if (l15 == hh*4 + rr) outv = p[hh][rr];
    scores[(size_t)(e0 + kg*4 + (l15 & 3))*4 + (l15 >> 2)] = outv;
  }

  // ---- fsum -> LDS (overlay, stride 36)
  #pragma unroll
  for (int c2 = 0; c2 < 2; c2++)
    #pragma unroll
    for (int r = 0; r < 4; r++)
      fsw[(kg*4 + r)*36 + c2*16 + l15] = fv[c2][r] + fv[c2+2][r] + fv[c2+4][r] + fv[c2+6][r];
  __builtin_amdgcn_sched_barrier(0);   // pin LDS writes before cross-lane reads

  // ---- phase 5: oe-KAN fully in-register
  float2 fsp[4];
  #pragma unroll
  for (int a = 0; a < 4; a++)
    fsp[a] = *(const float2*)&fsw[l15*36 + a*8 + kg*2];
  short8 afr5[8];
  #pragma unroll
  for (int ks = 0; ks < 8; ks++){
    int a = ks & 3;
    float tv[8];
    #pragma unroll
    for (int j = 0; j < 8; j++){
      float base = (j < 4) ? fsp[a].x : fsp[a].y;
      float xg = base * (float)((j & 3) + 1);
      tv[j] = (ks < 4) ? __cosf(xg) : __sinf(xg);
    }
    afr5[ks] = pack8(tv);
  }
  f32x4 oacc[2];
  __builtin_amdgcn_s_setprio(1);
  #pragma unroll
  for (int cg5 = 0; cg5 < 2; cg5++){
    f32x4 a = { oebv[cg5], oebv[cg5], oebv[cg5], oebv[cg5] };
    #pragma unroll
    for (int ks = 0; ks < 8; ks++){
      short8 bf = *(const short8*)(BOE + (size_t)(cg5*16 + l15)*256 + ks*32 + kg*8);
      a = MFMA(afr5[ks], bf, a);
    }
    oacc[cg5] = a;
  }
  __builtin_amdgcn_s_setprio(0);
  #pragma unroll
  for (int cg5 = 0; cg5 < 2; cg5++)
    #pragma unroll
    for (int r = 0; r < 4; r++)
      out_edge[(size_t)(e0 + kg*4 + r)*32 + cg5*16 + l15] = oacc[cg5][r];
}

// ---------------- per-node stats: softmax max/sum + mean agg ----------------
__global__ __launch_bounds__(256) void k_nodestats(
    const float* __restrict__ edge_feats, const float* __restrict__ scores,
    const int* __restrict__ off, const int* __restrict__ eids,
    float* __restrict__ agg, float* __restrict__ smax, float* __restrict__ rssum, int N)
{
  int n = blockIdx.x*4 + (threadIdx.x >> 6);
  int lane = threadIdx.x & 63;
  if (n >= N) return;
  int s0 = off[n], s1 = off[n+1], d = s1 - s0;
  float acc = 0.f;
  for (int t = s0; t < s1; t++){
    int eid = eids[t];
    acc += edge_feats[(size_t)eid*64 + lane];
  }
  agg[(size_t)n*64 + lane] = acc / (float)max(d, 1);
  if (lane < 4){
    float m = -1e30f;
    for (int t = s0; t < s1; t++) m = fmaxf(m, scores[(size_t)eids[t]*4 + lane]);
    float ss = 0.f;
    for (int t = s0; t < s1; t++) ss += __expf(scores[(size_t)eids[t]*4 + lane] - m);
    smax[n*4 + lane]  = (d > 0) ? m : 0.f;
    rssum[n*4 + lane] = (d > 0) ? 1.f/ss : 0.f;
  }
}

// ---------------- alpha precompute ----------------
__global__ void k_alpha(const float* __restrict__ scores, const int* __restrict__ dst,
                        const float* __restrict__ smax, const float* __restrict__ rssum,
                        float* __restrict__ alpha, int M){
  int t = blockIdx.x*256 + threadIdx.x;
  if (t < M){
    int e = t >> 2, hh = t & 3;
    int d = dst[e];
    alpha[t] = __expf(scores[t] - smax[d*4 + hh]) * rssum[d*4 + hh];
  }
}

// ---------------- h-aggregation ----------------
__global__ __launch_bounds__(256) void k_aggr(
    const float* __restrict__ h,        // [N][512]
    const float* __restrict__ alpha,    // [E][4]
    const int* __restrict__ src,
    const int* __restrict__ off, const int* __restrict__ eids,
    float* __restrict__ h_out, int N)
{
  __shared__ float part[256];
  int n = blockIdx.x;
  int tid = threadIdx.x;
  int ha = tid >> 7;
  int s0 = off[n], s1 = off[n+1];
  float acc_a = 0.f, acc_b = 0.f;
  for (int t = s0; t < s1; t++){
    int eid = eids[t];
    int sv = src[eid];
    float aa = alpha[(size_t)eid*4 + ha];
    float ab = alpha[(size_t)eid*4 + ha + 2];
    acc_a += aa * h[(size_t)sv*512 + tid];
    acc_b += ab * h[(size_t)sv*512 + 256 + tid];
  }
  part[tid] = leaky(acc_a) + leaky(acc_b);
  __syncthreads();
  if (tid < 128) h_out[(size_t)n*128 + tid] = part[tid] + part[tid + 128];
}

extern "C" void kernel_launch(void* const* d_in, const int* in_sizes, int n_in,
                              void* d_out, int out_size, void* d_ws, size_t ws_size,
                              hipStream_t stream){
  const float* node_feats = (const float*)d_in[0];
  const float* edge_feats = (const float*)d_in[1];
  const int*   src        = (const int*)  d_in[2];
  const int*   dst        = (const int*)  d_in[3];
  const float* W_ni       = (const float*)d_in[4];
  const float* W_nj       = (const float*)d_in[5];
  const float* W_fij      = (const float*)d_in[6];
  const float* W_node     = (const float*)d_in[7];
  const float* b_node     = (const float*)d_in[8];
  const float* attn       = (const float*)d_in[9];
  const float* bias_edge  = (const float*)d_in[10];
  const float* ek_c       = (const float*)d_in[11];
  const float* ek_b       = (const float*)d_in[12];
  const float* nk_c       = (const float*)d_in[13];
  const float* nk_b       = (const float*)d_in[14];
  const float* on_c       = (const float*)d_in[15];
  const float* on_b       = (const float*)d_in[16];
  const float* oe_c       = (const float*)d_in[17];
  const float* oe_b       = (const float*)d_in[18];

  const int N = in_sizes[0] / 128;
  const int E = in_sizes[2];

  float* ws = (float*)d_ws;
  size_t o = 0;
  float* P      = ws + o; o += (size_t)N*256;
  float* scores = ws + o; o += (size_t)E*4;
  float* smax   = ws + o; o += (size_t)N*4;
  float* rssum  = ws + o; o += (size_t)N*4;
  float* agg    = ws + o; o += (size_t)N*64;
  float* mk     = ws + o; o += (size_t)N*192;
  float* h      = ws + o; o += (size_t)N*512;
  float* h_out  = ws + o; o += (size_t)N*128;
  o = (o + 7) & ~(size_t)7;
  ushort* Bni  = (ushort*)(ws + o); o += 8192;    // Bni+Bnj contiguous -> one [256][128] B
  ushort* Bnj  = (ushort*)(ws + o); o += 8192;
  ushort* Bfij = (ushort*)(ws + o); o += 4096;
  ushort* BE   = (ushort*)(ws + o); o += 16384;
  ushort* BN_  = (ushort*)(ws + o); o += 36864;
  ushort* BW   = (ushort*)(ws + o); o += 49152;
  ushort* BO   = (ushort*)(ws + o); o += 65536;
  ushort* BOE  = (ushort*)(ws + o); o += 4096;
  int* deg    = (int*)(ws + o); o += N;
  int* cursor = (int*)(ws + o); o += N;
  int* off    = (int*)(ws + o); o += (size_t)(N + 1);
  int* eids   = (int*)(ws + o); o += E;

  float* alpha = P;   // reuse: P dead after k_edge, alpha written after

  float* out_node = (float*)d_out;
  float* out_edge = (float*)d_out + (size_t)N*128;

  (void)hipMemsetAsync(deg, 0, sizeof(int)*(size_t)(2*N), stream);   // deg + cursor

  k_deg <<<(E + 255)/256, 256, 0, stream>>>(dst, deg, E);
  k_scan<<<1, 1024, 0, stream>>>(deg, off, N);
  k_fill<<<(E + 255)/256, 256, 0, stream>>>(dst, off, cursor, eids, E);
  k_prep2<<<1505, 256, 0, stream>>>(W_ni, W_nj, W_fij, W_node, ek_c, nk_c, on_c, oe_c,
                                    Bni, Bnj, Bfij, BE, BN_, BW, BO, BOE);

  const int MB = (N + 63)/64;
  // P = node_feats @ [W_ni | W_nj]  (Bni,Bnj adjacent -> single GEMM over 256 cols)
  k_mm<0><<<dim3(MB, 4), 256, 0, stream>>>(node_feats, 128, nullptr, Bni, P, 256, nullptr, N, 128);

  k_edge<<<(E + 63)/64, 256, 0, stream>>>(P, edge_feats, src, dst, Bfij, BE, BOE,
                                          ek_b, bias_edge, attn, oe_b, scores, out_edge, E);

  k_nodestats<<<(N + 3)/4, 256, 0, stream>>>(edge_feats, scores, off, eids, agg, smax, rssum, N);
  k_alpha<<<(E*4 + 255)/256, 256, 0, stream>>>(scores, dst, smax, rssum, alpha, E*4);

  k_mm<2><<<dim3(MB, 3), 256, 0, stream>>>(node_feats, 128, agg, BN_, mk, 192, nk_b, N, 384);
  k_mm<0><<<dim3(MB, 8), 256, 0, stream>>>(mk, 192, nullptr, BW, h, 512, b_node, N, 192);

  k_aggr<<<N, 256, 0, stream>>>(h, alpha, src, off, eids, h_out, N);

  k_mm<1><<<dim3(MB, 2), 256, 0, stream>>>(h_out, 128, nullptr, BO, out_node, 128, on_b, N, 1024);
}